// Round 1
// baseline (532.296 us; speedup 1.0000x reference)
//
#include <hip/hip_runtime.h>
#include <hip/hip_bf16.h>
#include <stdint.h>

// EdgeConv: h_theta = feat@Wt, h_phi = feat@Wp
//           out[i] = max_k h_theta[src[i,k]] + (h_phi[i] - h_theta[i])
// N=65536, F=512, K=16.
//
// Pipeline:
//  k_convert_feat : feat f32 -> bf16 (ws, 64MB)
//  k_prep_w       : Wcat^T (1024x512) bf16 (ws, 1MB)  [row n contiguous in k]
//  k_gemm         : bf16 MFMA 128x128 tile; n<512 -> theta table (bf16, ws 64MB)
//                   n>=512 -> phi (f32) into d_out
//  k_gather       : out[i,c] = max_k theta[src[i,k]][c] + phi[i,c] - theta[i][c]

typedef __bf16 bf16x8 __attribute__((ext_vector_type(8)));
typedef float f32x4 __attribute__((ext_vector_type(4)));

__device__ __forceinline__ unsigned short f2bf(float x) {
    unsigned u = __float_as_uint(x);
    unsigned r = u + 0x7fffu + ((u >> 16) & 1u);   // RNE
    return (unsigned short)(r >> 16);
}
__device__ __forceinline__ float bf2f(unsigned short b) {
    return __uint_as_float(((unsigned)b) << 16);
}

__device__ __forceinline__ void async_ld16(const void* g, void* l) {
    __builtin_amdgcn_global_load_lds(
        (const __attribute__((address_space(1))) unsigned int*)g,
        (__attribute__((address_space(3))) unsigned int*)l,
        16, 0, 0);
}

// ---------------- feat f32 -> bf16 ----------------
__global__ void k_convert_feat(const float* __restrict__ feat,
                               unsigned short* __restrict__ featb) {
    int i = (blockIdx.x * 256 + threadIdx.x) * 4;
    float4 f = *(const float4*)(feat + i);
    ushort4 o;
    o.x = f2bf(f.x); o.y = f2bf(f.y); o.z = f2bf(f.z); o.w = f2bf(f.w);
    *(ushort4*)(featb + i) = o;
}

// ---------------- Wcat^T: wtc[n][k] = (n<512 ? Wth[k][n] : Wph[k][n-512]) ----------------
__global__ void k_prep_w(const float* __restrict__ Wth,
                         const float* __restrict__ Wph,
                         unsigned short* __restrict__ wtc) {
    int o = blockIdx.x * 256 + threadIdx.x;   // 0 .. 1024*512-1
    int n = o >> 9;
    int kk = o & 511;
    float v = (n < 512) ? Wth[kk * 512 + n] : Wph[kk * 512 + (n - 512)];
    wtc[o] = f2bf(v);
}

// ---------------- bf16 MFMA GEMM: C (N x 1024) = featb (N x 512) @ Wcat ----------------
// 128x128 tile, BK=32, 256 thr = 4 waves (2x2 of 64x64), 16x16x32 MFMA.
__global__ void k_gemm(const unsigned short* __restrict__ A,   // N x 512 bf16
                       const unsigned short* __restrict__ Bt,  // 1024 x 512 bf16 (B^T)
                       unsigned short* __restrict__ theta,     // N x 512 bf16
                       float* __restrict__ phi_out)            // N x 512 f32
{
    __shared__ __align__(16) unsigned short As[128 * 32];
    __shared__ __align__(16) unsigned short Bs[128 * 32];

    const int tid  = threadIdx.x;
    const int wave = tid >> 6;
    const int lane = tid & 63;
    const int quad = lane >> 4;
    const int l15  = lane & 15;

    const int nt = blockIdx.x & 7;
    const int mt = blockIdx.x >> 3;
    const int m0 = mt * 128;
    const int n0 = nt * 128;

    const int wm = wave >> 1;
    const int wn = wave & 1;

    f32x4 acc[4][4];
#pragma unroll
    for (int i = 0; i < 4; i++)
#pragma unroll
        for (int j = 0; j < 4; j++) acc[i][j] = (f32x4){0.f, 0.f, 0.f, 0.f};

    // staging: per wave 2 insts for A, 2 for B; LDS dest = base + lane*16 (contiguous)
    const int r0   = (wave * 2 + 0) * 16 + (lane >> 2);
    const int r1   = (wave * 2 + 1) * 16 + (lane >> 2);
    const int koff = (lane & 3) * 8;   // element offset within 32-wide k-tile

    const unsigned short* Ag0 = A  + (size_t)(m0 + r0) * 512 + koff;
    const unsigned short* Ag1 = A  + (size_t)(m0 + r1) * 512 + koff;
    const unsigned short* Bg0 = Bt + (size_t)(n0 + r0) * 512 + koff;
    const unsigned short* Bg1 = Bt + (size_t)(n0 + r1) * 512 + koff;

    unsigned short* lA0 = &As[(wave * 2 + 0) * 512];
    unsigned short* lA1 = &As[(wave * 2 + 1) * 512];
    unsigned short* lB0 = &Bs[(wave * 2 + 0) * 512];
    unsigned short* lB1 = &Bs[(wave * 2 + 1) * 512];

    for (int kt = 0; kt < 16; ++kt) {
        const int kg = kt * 32;
        __syncthreads();
        async_ld16(Ag0 + kg, lA0);
        async_ld16(Ag1 + kg, lA1);
        async_ld16(Bg0 + kg, lB0);
        async_ld16(Bg1 + kg, lB1);
        __syncthreads();   // compiler emits vmcnt(0) drain before s_barrier

        bf16x8 af[4], bfr[4];
#pragma unroll
        for (int t = 0; t < 4; ++t) {
            const int am = wm * 64 + t * 16 + l15;
            af[t]  = *(const bf16x8*)&As[am * 32 + quad * 8];
            const int bn = wn * 64 + t * 16 + l15;
            bfr[t] = *(const bf16x8*)&Bs[bn * 32 + quad * 8];
        }
#pragma unroll
        for (int i = 0; i < 4; i++)
#pragma unroll
            for (int j = 0; j < 4; j++)
                acc[i][j] = __builtin_amdgcn_mfma_f32_16x16x32_bf16(af[i], bfr[j], acc[i][j], 0, 0, 0);
    }

    // epilogue: D col = lane&15, row = quad*4 + r  [verified layout, m89]
    const bool is_phi = (n0 >= 512);
#pragma unroll
    for (int i = 0; i < 4; i++) {
        const int mrow = m0 + wm * 64 + i * 16 + quad * 4;
#pragma unroll
        for (int j = 0; j < 4; j++) {
            const int ncol = n0 + wn * 64 + j * 16 + l15;
#pragma unroll
            for (int r = 0; r < 4; r++) {
                const float v = acc[i][j][r];
                if (is_phi) {
                    phi_out[(size_t)(mrow + r) * 512 + (ncol - 512)] = v;
                } else {
                    theta[(size_t)(mrow + r) * 512 + ncol] = f2bf(v);
                }
            }
        }
    }
}

// ---------------- gather + max + combine ----------------
// 1 block per row, 256 threads, 2 cols/thread (uint = 2 bf16 from table).
__global__ void k_gather(const unsigned short* __restrict__ theta,
                         float* out,                      // holds phi on entry
                         const int* __restrict__ src,
                         const int* __restrict__ kptr,
                         int srcStride)
{
    const int row = blockIdx.x;
    const int c   = threadIdx.x * 2;
    const int kk  = *kptr;
    const int base = row * srcStride;

    float m0 = -INFINITY, m1 = -INFINITY;
    if (kk == 16) {
#pragma unroll
        for (int k = 0; k < 16; ++k) {
            const int s = src[base + k];
            const unsigned v = *(const unsigned*)(theta + (size_t)s * 512 + c);
            m0 = fmaxf(m0, bf2f((unsigned short)(v & 0xffffu)));
            m1 = fmaxf(m1, bf2f((unsigned short)(v >> 16)));
        }
    } else {
        for (int k = 0; k < kk; ++k) {
            const int s = src[base + k];
            const unsigned v = *(const unsigned*)(theta + (size_t)s * 512 + c);
            m0 = fmaxf(m0, bf2f((unsigned short)(v & 0xffffu)));
            m1 = fmaxf(m1, bf2f((unsigned short)(v >> 16)));
        }
    }

    const unsigned tv = *(const unsigned*)(theta + (size_t)row * 512 + c);
    const float2 ph = *(const float2*)(out + (size_t)row * 512 + c);
    float2 o;
    o.x = m0 + ph.x - bf2f((unsigned short)(tv & 0xffffu));
    o.y = m1 + ph.y - bf2f((unsigned short)(tv >> 16));
    *(float2*)(out + (size_t)row * 512 + c) = o;
}

extern "C" void kernel_launch(void* const* d_in, const int* in_sizes, int n_in,
                              void* d_out, int out_size, void* d_ws, size_t ws_size,
                              hipStream_t stream) {
    const int*   kptr = (const int*)d_in[0];
    const int*   src  = (const int*)d_in[1];
    const float* feat = (const float*)d_in[2];
    const float* Wth  = (const float*)d_in[3];
    const float* Wph  = (const float*)d_in[4];
    float* out = (float*)d_out;

    const int N = in_sizes[2] / 512;          // 65536
    const int srcStride = in_sizes[1] / N;    // 16

    // workspace layout (needs 129 MB)
    unsigned short* featb = (unsigned short*)d_ws;                                    // 64 MB
    unsigned short* wtc   = (unsigned short*)((char*)d_ws + (size_t)64 * 1024 * 1024); // 1 MB
    unsigned short* table = (unsigned short*)((char*)d_ws + (size_t)65 * 1024 * 1024); // 64 MB

    k_convert_feat<<<(N * 512) / 1024, 256, 0, stream>>>(feat, featb);
    k_prep_w<<<(1024 * 512) / 256, 256, 0, stream>>>(Wth, Wph, wtc);
    k_gemm<<<(N / 128) * 8, 256, 0, stream>>>(featb, wtc, table, out);
    k_gather<<<N, 256, 0, stream>>>(table, out, src, kptr, srcStride);
}

// Round 2
// 475.756 us; speedup vs baseline: 1.1188x; 1.1188x over previous
//
#include <hip/hip_runtime.h>
#include <hip/hip_bf16.h>
#include <stdint.h>

// EdgeConv: out[i] = max_k h_theta[src[i,k]] + (h_phi - h_theta)[i]
//         = max_k theta[src[i,k]] + feat @ (W_phi - W_theta)   (delta trick)
// N=65536, F=512, K=16.
//
// Pipeline:
//  k_convert_feat : feat f32 -> bf16 (ws, 64MB)
//  k_prep_w       : Wcat^T (1024x512) bf16, LDS-transposed; rows 512.. hold
//                   (W_phi - W_theta)^T so GEMM directly produces delta
//  k_gemm         : 128x128 bf16 MFMA tile, XCD-swizzled blockIdx so the 8
//                   n-blocks sharing an A-tile run adjacent on ONE XCD
//  k_gather       : out[i,c] = max_k theta[src[i,k]][c] + delta[i,c]

typedef __bf16 bf16x8 __attribute__((ext_vector_type(8)));
typedef float f32x4 __attribute__((ext_vector_type(4)));

__device__ __forceinline__ unsigned short f2bf(float x) {
    unsigned u = __float_as_uint(x);
    unsigned r = u + 0x7fffu + ((u >> 16) & 1u);   // RNE
    return (unsigned short)(r >> 16);
}
__device__ __forceinline__ float bf2f(unsigned short b) {
    return __uint_as_float(((unsigned)b) << 16);
}

__device__ __forceinline__ void async_ld16(const void* g, void* l) {
    __builtin_amdgcn_global_load_lds(
        (const __attribute__((address_space(1))) unsigned int*)g,
        (__attribute__((address_space(3))) unsigned int*)l,
        16, 0, 0);
}

// ---------------- feat f32 -> bf16 ----------------
__global__ void k_convert_feat(const float* __restrict__ feat,
                               unsigned short* __restrict__ featb) {
    int i = (blockIdx.x * 256 + threadIdx.x) * 4;
    float4 f = *(const float4*)(feat + i);
    ushort4 o;
    o.x = f2bf(f.x); o.y = f2bf(f.y); o.z = f2bf(f.z); o.w = f2bf(f.w);
    *(ushort4*)(featb + i) = o;
}

// ---------------- Wcat^T via LDS transpose ----------------
// wtc[n][k]:  n<512 -> Wth[k][n] ;  n>=512 -> Wph[k][n-512] - Wth[k][n-512]
// 32x32 tiles, coalesced read AND write, 33-pad kills bank conflicts.
__global__ void k_prep_w(const float* __restrict__ Wth,
                         const float* __restrict__ Wph,
                         unsigned short* __restrict__ wtc) {
    __shared__ float tile[32][33];
    const int k0 = (blockIdx.x & 15) * 32;   // 512/32 = 16 k-tiles
    const int n0 = (blockIdx.x >> 4) * 32;   // 1024/32 = 32 n-tiles
    const int t  = threadIdx.x;
    const int cc = t & 31;
    const int r0 = t >> 5;                   // 0..7
#pragma unroll
    for (int it = 0; it < 4; ++it) {
        const int r  = it * 8 + r0;          // k within tile
        const int gn = n0 + cc;
        float v;
        if (gn < 512) v = Wth[(k0 + r) * 512 + gn];
        else          v = Wph[(k0 + r) * 512 + (gn - 512)] - Wth[(k0 + r) * 512 + (gn - 512)];
        tile[r][cc] = v;
    }
    __syncthreads();
#pragma unroll
    for (int it = 0; it < 4; ++it) {
        const int r2 = t & 31;               // k (contiguous in wtc row)
        const int c2 = it * 8 + (t >> 5);    // n within tile
        wtc[(size_t)(n0 + c2) * 512 + k0 + r2] = f2bf(tile[r2][c2]);
    }
}

// ---------------- bf16 MFMA GEMM: C (N x 1024) = featb @ Wcat ----------------
// 128x128 tile, BK=32, 256 thr = 4 waves (2x2 of 64x64), 16x16x32 MFMA.
// blockIdx decode: x=b&7 (XCD via i%8 round-robin), nt=(b>>3)&7, mt=(b>>6)*8+x.
// -> the 8 blocks sharing one A-tile are temporally adjacent on one XCD,
//    so the A-tile is fetched into that XCD's L2 once (~12 live tiles=1.5MB).
__global__ void k_gemm(const unsigned short* __restrict__ A,   // N x 512 bf16
                       const unsigned short* __restrict__ Bt,  // 1024 x 512 bf16
                       unsigned short* __restrict__ theta,     // N x 512 bf16
                       unsigned short* __restrict__ delta_b,   // N x 512 bf16 (if dbf)
                       float* __restrict__ delta_f,            // N x 512 f32  (else)
                       int dbf)
{
    __shared__ __align__(16) unsigned short As[128 * 32];
    __shared__ __align__(16) unsigned short Bs[128 * 32];

    const int tid  = threadIdx.x;
    const int wave = tid >> 6;
    const int lane = tid & 63;
    const int quad = lane >> 4;
    const int l15  = lane & 15;

    const int b  = blockIdx.x;
    const int mt = (b >> 6) * 8 + (b & 7);
    const int nt = (b >> 3) & 7;
    const int m0 = mt * 128;
    const int n0 = nt * 128;

    const int wm = wave >> 1;
    const int wn = wave & 1;

    f32x4 acc[4][4];
#pragma unroll
    for (int i = 0; i < 4; i++)
#pragma unroll
        for (int j = 0; j < 4; j++) acc[i][j] = (f32x4){0.f, 0.f, 0.f, 0.f};

    const int r0   = (wave * 2 + 0) * 16 + (lane >> 2);
    const int r1   = (wave * 2 + 1) * 16 + (lane >> 2);
    const int koff = (lane & 3) * 8;

    const unsigned short* Ag0 = A  + (size_t)(m0 + r0) * 512 + koff;
    const unsigned short* Ag1 = A  + (size_t)(m0 + r1) * 512 + koff;
    const unsigned short* Bg0 = Bt + (size_t)(n0 + r0) * 512 + koff;
    const unsigned short* Bg1 = Bt + (size_t)(n0 + r1) * 512 + koff;

    unsigned short* lA0 = &As[(wave * 2 + 0) * 512];
    unsigned short* lA1 = &As[(wave * 2 + 1) * 512];
    unsigned short* lB0 = &Bs[(wave * 2 + 0) * 512];
    unsigned short* lB1 = &Bs[(wave * 2 + 1) * 512];

    for (int kt = 0; kt < 16; ++kt) {
        const int kg = kt * 32;
        __syncthreads();
        async_ld16(Ag0 + kg, lA0);
        async_ld16(Ag1 + kg, lA1);
        async_ld16(Bg0 + kg, lB0);
        async_ld16(Bg1 + kg, lB1);
        __syncthreads();   // vmcnt(0) drain before s_barrier

        bf16x8 af[4], bfr[4];
#pragma unroll
        for (int t = 0; t < 4; ++t) {
            const int am = wm * 64 + t * 16 + l15;
            af[t]  = *(const bf16x8*)&As[am * 32 + quad * 8];
            const int bn = wn * 64 + t * 16 + l15;
            bfr[t] = *(const bf16x8*)&Bs[bn * 32 + quad * 8];
        }
#pragma unroll
        for (int i = 0; i < 4; i++)
#pragma unroll
            for (int j = 0; j < 4; j++)
                acc[i][j] = __builtin_amdgcn_mfma_f32_16x16x32_bf16(af[i], bfr[j], acc[i][j], 0, 0, 0);
    }

    // D layout: col = lane&15, row = quad*4 + r  [verified, m89]
    const bool is_theta = (n0 < 512);
#pragma unroll
    for (int i = 0; i < 4; i++) {
        const int mrow = m0 + wm * 64 + i * 16 + quad * 4;
#pragma unroll
        for (int j = 0; j < 4; j++) {
            const int ncol = n0 + wn * 64 + j * 16 + l15;
#pragma unroll
            for (int r = 0; r < 4; r++) {
                const float v = acc[i][j][r];
                if (is_theta) {
                    theta[(size_t)(mrow + r) * 512 + ncol] = f2bf(v);
                } else if (dbf) {
                    delta_b[(size_t)(mrow + r) * 512 + (ncol - 512)] = f2bf(v);
                } else {
                    delta_f[(size_t)(mrow + r) * 512 + (ncol - 512)] = v;
                }
            }
        }
    }
}

// ---------------- gather + max + combine ----------------
// 2 rows per 256-thread block, 4 cols/thread (uint2 = 4 bf16 per gather).
__global__ void k_gather(const unsigned short* __restrict__ theta,
                         const unsigned short* __restrict__ delta_b,
                         float* out,                      // f32-delta path: holds delta
                         const int* __restrict__ src,
                         const int* __restrict__ kptr,
                         int srcStride, int dbf)
{
    const int row = (blockIdx.x << 1) + (threadIdx.x >> 7);
    const int c   = (threadIdx.x & 127) << 2;
    const int kk  = *kptr;
    const size_t base = (size_t)row * srcStride;

    float m0 = -INFINITY, m1 = -INFINITY, m2 = -INFINITY, m3 = -INFINITY;
    if (kk == 16) {
#pragma unroll
        for (int k = 0; k < 16; ++k) {
            const int s = src[base + k];
            const uint2 v = *(const uint2*)(theta + (size_t)s * 512 + c);
            m0 = fmaxf(m0, bf2f((unsigned short)(v.x & 0xffffu)));
            m1 = fmaxf(m1, bf2f((unsigned short)(v.x >> 16)));
            m2 = fmaxf(m2, bf2f((unsigned short)(v.y & 0xffffu)));
            m3 = fmaxf(m3, bf2f((unsigned short)(v.y >> 16)));
        }
    } else {
        for (int k = 0; k < kk; ++k) {
            const int s = src[base + k];
            const uint2 v = *(const uint2*)(theta + (size_t)s * 512 + c);
            m0 = fmaxf(m0, bf2f((unsigned short)(v.x & 0xffffu)));
            m1 = fmaxf(m1, bf2f((unsigned short)(v.x >> 16)));
            m2 = fmaxf(m2, bf2f((unsigned short)(v.y & 0xffffu)));
            m3 = fmaxf(m3, bf2f((unsigned short)(v.y >> 16)));
        }
    }

    float d0, d1, d2, d3;
    if (dbf) {
        const uint2 dv = *(const uint2*)(delta_b + (size_t)row * 512 + c);
        d0 = bf2f((unsigned short)(dv.x & 0xffffu));
        d1 = bf2f((unsigned short)(dv.x >> 16));
        d2 = bf2f((unsigned short)(dv.y & 0xffffu));
        d3 = bf2f((unsigned short)(dv.y >> 16));
    } else {
        const float4 dv = *(const float4*)(out + (size_t)row * 512 + c);
        d0 = dv.x; d1 = dv.y; d2 = dv.z; d3 = dv.w;
    }
    float4 o;
    o.x = m0 + d0; o.y = m1 + d1; o.z = m2 + d2; o.w = m3 + d3;
    *(float4*)(out + (size_t)row * 512 + c) = o;
}

extern "C" void kernel_launch(void* const* d_in, const int* in_sizes, int n_in,
                              void* d_out, int out_size, void* d_ws, size_t ws_size,
                              hipStream_t stream) {
    const int*   kptr = (const int*)d_in[0];
    const int*   src  = (const int*)d_in[1];
    const float* feat = (const float*)d_in[2];
    const float* Wth  = (const float*)d_in[3];
    const float* Wph  = (const float*)d_in[4];
    float* out = (float*)d_out;

    const int N = in_sizes[2] / 512;          // 65536
    const int srcStride = in_sizes[1] / N;    // 16

    // ws layout: featb 64MB | wtc 1MB | theta 64MB | delta_b 64MB (optional)
    unsigned short* featb   = (unsigned short*)d_ws;
    unsigned short* wtc     = (unsigned short*)((char*)d_ws + (size_t)64 * 1024 * 1024);
    unsigned short* table   = (unsigned short*)((char*)d_ws + (size_t)65 * 1024 * 1024);
    unsigned short* delta_b = (unsigned short*)((char*)d_ws + (size_t)129 * 1024 * 1024);
    const int dbf = (ws_size >= (size_t)194 * 1024 * 1024) ? 1 : 0;

    k_convert_feat<<<(N * 512) / 1024, 256, 0, stream>>>(feat, featb);
    k_prep_w<<<512, 256, 0, stream>>>(Wth, Wph, wtc);
    k_gemm<<<(N / 128) * 8, 256, 0, stream>>>(featb, wtc, table, delta_b, out, dbf);
    k_gather<<<N / 2, 256, 0, stream>>>(table, delta_b, out, src, kptr, srcStride, dbf);
}

// Round 3
// 463.244 us; speedup vs baseline: 1.1491x; 1.0270x over previous
//
#include <hip/hip_runtime.h>
#include <hip/hip_bf16.h>
#include <stdint.h>

// EdgeConv: out[i] = max_k theta[src[i,k]] + feat @ (W_phi - W_theta)
// N=65536, F=512, K=16.
//
// Pipeline:
//  k_convert_feat : feat f32 -> bf16 (ws, 64MB), nt loads
//  k_prep_w       : Wcat^T (1024x512) bf16, LDS-transposed; cols 512.. hold
//                   (W_phi - W_theta)^T so GEMM directly produces delta
//  k_gemm         : 128x128 bf16 MFMA tile, XCD-swizzled blockIdx;
//                   theta written in SLAB layout: 16 slabs of [N x 32] bf16
//                   (4 MB each == one XCD L2); delta f32 -> d_out
//  k_gather       : column-sliced + XCD-affine: block b -> XCD b%8 handles
//                   slice (phase*8 + b%8); its 4MB slab stays L2-resident.
//                   delta-read / out-write are non-temporal (don't evict).

typedef __bf16 bf16x8 __attribute__((ext_vector_type(8)));
typedef float f32x4 __attribute__((ext_vector_type(4)));

__device__ __forceinline__ unsigned short f2bf(float x) {
    unsigned u = __float_as_uint(x);
    unsigned r = u + 0x7fffu + ((u >> 16) & 1u);   // RNE
    return (unsigned short)(r >> 16);
}

__device__ __forceinline__ void async_ld16(const void* g, void* l) {
    __builtin_amdgcn_global_load_lds(
        (const __attribute__((address_space(1))) unsigned int*)g,
        (__attribute__((address_space(3))) unsigned int*)l,
        16, 0, 0);
}

// ---------------- feat f32 -> bf16 ----------------
__global__ void k_convert_feat(const float* __restrict__ feat,
                               unsigned short* __restrict__ featb) {
    int i = (blockIdx.x * 256 + threadIdx.x) * 4;
    f32x4 f = __builtin_nontemporal_load((const f32x4*)(feat + i));
    ushort4 o;
    o.x = f2bf(f.x); o.y = f2bf(f.y); o.z = f2bf(f.z); o.w = f2bf(f.w);
    *(ushort4*)(featb + i) = o;
}

// ---------------- Wcat^T via LDS transpose ----------------
// wtc[n][k]:  n<512 -> Wth[k][n] ;  n>=512 -> Wph[k][n-512] - Wth[k][n-512]
__global__ void k_prep_w(const float* __restrict__ Wth,
                         const float* __restrict__ Wph,
                         unsigned short* __restrict__ wtc) {
    __shared__ float tile[32][33];
    const int k0 = (blockIdx.x & 15) * 32;
    const int n0 = (blockIdx.x >> 4) * 32;
    const int t  = threadIdx.x;
    const int cc = t & 31;
    const int r0 = t >> 5;
#pragma unroll
    for (int it = 0; it < 4; ++it) {
        const int r  = it * 8 + r0;
        const int gn = n0 + cc;
        float v;
        if (gn < 512) v = Wth[(k0 + r) * 512 + gn];
        else          v = Wph[(k0 + r) * 512 + (gn - 512)] - Wth[(k0 + r) * 512 + (gn - 512)];
        tile[r][cc] = v;
    }
    __syncthreads();
#pragma unroll
    for (int it = 0; it < 4; ++it) {
        const int r2 = t & 31;
        const int c2 = it * 8 + (t >> 5);
        wtc[(size_t)(n0 + c2) * 512 + k0 + r2] = f2bf(tile[r2][c2]);
    }
}

// ---------------- bf16 MFMA GEMM: C (N x 1024) = featb @ Wcat ----------------
// 128x128 tile, BK=32, 256 thr = 4 waves (2x2 of 64x64), 16x16x32 MFMA.
// theta (n<512) -> slab layout: theta[(n>>5)*slabStride + row*32 + (n&31)]
// delta (n>=512) -> f32 into out (row-major N x 512)
__global__ void k_gemm(const unsigned short* __restrict__ A,   // N x 512 bf16
                       const unsigned short* __restrict__ Bt,  // 1024 x 512 bf16
                       unsigned short* __restrict__ theta,     // 16 slabs of N x 32
                       float* __restrict__ delta_f,            // N x 512 f32
                       size_t slabStride)
{
    __shared__ __align__(16) unsigned short As[128 * 32];
    __shared__ __align__(16) unsigned short Bs[128 * 32];

    const int tid  = threadIdx.x;
    const int wave = tid >> 6;
    const int lane = tid & 63;
    const int quad = lane >> 4;
    const int l15  = lane & 15;

    const int b  = blockIdx.x;
    const int mt = (b >> 6) * 8 + (b & 7);
    const int nt = (b >> 3) & 7;
    const int m0 = mt * 128;
    const int n0 = nt * 128;

    const int wm = wave >> 1;
    const int wn = wave & 1;

    f32x4 acc[4][4];
#pragma unroll
    for (int i = 0; i < 4; i++)
#pragma unroll
        for (int j = 0; j < 4; j++) acc[i][j] = (f32x4){0.f, 0.f, 0.f, 0.f};

    const int r0   = (wave * 2 + 0) * 16 + (lane >> 2);
    const int r1   = (wave * 2 + 1) * 16 + (lane >> 2);
    const int koff = (lane & 3) * 8;

    const unsigned short* Ag0 = A  + (size_t)(m0 + r0) * 512 + koff;
    const unsigned short* Ag1 = A  + (size_t)(m0 + r1) * 512 + koff;
    const unsigned short* Bg0 = Bt + (size_t)(n0 + r0) * 512 + koff;
    const unsigned short* Bg1 = Bt + (size_t)(n0 + r1) * 512 + koff;

    unsigned short* lA0 = &As[(wave * 2 + 0) * 512];
    unsigned short* lA1 = &As[(wave * 2 + 1) * 512];
    unsigned short* lB0 = &Bs[(wave * 2 + 0) * 512];
    unsigned short* lB1 = &Bs[(wave * 2 + 1) * 512];

    for (int kt = 0; kt < 16; ++kt) {
        const int kg = kt * 32;
        __syncthreads();
        async_ld16(Ag0 + kg, lA0);
        async_ld16(Ag1 + kg, lA1);
        async_ld16(Bg0 + kg, lB0);
        async_ld16(Bg1 + kg, lB1);
        __syncthreads();   // vmcnt(0) drain before s_barrier

        bf16x8 af[4], bfr[4];
#pragma unroll
        for (int t = 0; t < 4; ++t) {
            const int am = wm * 64 + t * 16 + l15;
            af[t]  = *(const bf16x8*)&As[am * 32 + quad * 8];
            const int bn = wn * 64 + t * 16 + l15;
            bfr[t] = *(const bf16x8*)&Bs[bn * 32 + quad * 8];
        }
#pragma unroll
        for (int i = 0; i < 4; i++)
#pragma unroll
            for (int j = 0; j < 4; j++)
                acc[i][j] = __builtin_amdgcn_mfma_f32_16x16x32_bf16(af[i], bfr[j], acc[i][j], 0, 0, 0);
    }

    // D layout: col = lane&15, row = quad*4 + r  [verified, m89]
    const bool is_theta = (n0 < 512);
#pragma unroll
    for (int i = 0; i < 4; i++) {
        const int mrow = m0 + wm * 64 + i * 16 + quad * 4;
#pragma unroll
        for (int j = 0; j < 4; j++) {
            const int ncol = n0 + wn * 64 + j * 16 + l15;
#pragma unroll
            for (int r = 0; r < 4; r++) {
                const float v = acc[i][j][r];
                if (is_theta) {
                    theta[(size_t)(ncol >> 5) * slabStride
                          + (size_t)(mrow + r) * 32 + (ncol & 31)] = f2bf(v);
                } else {
                    delta_f[(size_t)(mrow + r) * 512 + (ncol - 512)] = v;
                }
            }
        }
    }
}

// ---------------- column-sliced gather + max + combine ----------------
// grid = 16 slices x (N/512) chunks. Block b: xcd = b&7; the first
// 8*chunksPerSlice blocks are phase 0 (slices 0..7), rest slices 8..15.
// Each block: 512 rows x 32 cols; 256 thr = 4 thr/row x 64 rows/pass, 8 passes.
// Per thread: 8 cols (16 B uint4 per gather).
__global__ void k_gather(const unsigned short* __restrict__ theta,
                         float* out,                      // holds delta f32 on entry
                         const int* __restrict__ src,
                         const int* __restrict__ kptr,
                         int chunksPerSlice, size_t slabStride)
{
    const int b     = blockIdx.x;
    const int xcd   = b & 7;
    const int t2    = b >> 3;
    const int chunk = t2 % chunksPerSlice;
    const int phase = t2 / chunksPerSlice;       // 0 or 1
    const int slice = phase * 8 + xcd;
    const int kk    = *kptr;

    const unsigned short* slab = theta + (size_t)slice * slabStride;
    const int tid = threadIdx.x;
    const int c8  = (tid & 3) * 8;               // col within 32-wide slice
    const int rly = tid >> 2;                    // 0..63

#pragma unroll 2
    for (int pass = 0; pass < 8; ++pass) {
        const int row = chunk * 512 + pass * 64 + rly;

        float m0 = -INFINITY, m1 = -INFINITY, m2 = -INFINITY, m3 = -INFINITY;
        float m4 = -INFINITY, m5 = -INFINITY, m6 = -INFINITY, m7 = -INFINITY;

        if (kk == 16) {
            const int4* sp = (const int4*)(src + (size_t)row * 16);
            int4 sv[4];
            sv[0] = sp[0]; sv[1] = sp[1]; sv[2] = sp[2]; sv[3] = sp[3];
#pragma unroll
            for (int q = 0; q < 4; ++q) {
                const int ss[4] = {sv[q].x, sv[q].y, sv[q].z, sv[q].w};
#pragma unroll
                for (int j = 0; j < 4; ++j) {
                    const uint4 v = *(const uint4*)(slab + (size_t)ss[j] * 32 + c8);
                    m0 = fmaxf(m0, __uint_as_float(v.x << 16));
                    m1 = fmaxf(m1, __uint_as_float(v.x & 0xffff0000u));
                    m2 = fmaxf(m2, __uint_as_float(v.y << 16));
                    m3 = fmaxf(m3, __uint_as_float(v.y & 0xffff0000u));
                    m4 = fmaxf(m4, __uint_as_float(v.z << 16));
                    m5 = fmaxf(m5, __uint_as_float(v.z & 0xffff0000u));
                    m6 = fmaxf(m6, __uint_as_float(v.w << 16));
                    m7 = fmaxf(m7, __uint_as_float(v.w & 0xffff0000u));
                }
            }
        } else {
            for (int k = 0; k < kk; ++k) {
                const int s = src[(size_t)row * 16 + k];
                const uint4 v = *(const uint4*)(slab + (size_t)s * 32 + c8);
                m0 = fmaxf(m0, __uint_as_float(v.x << 16));
                m1 = fmaxf(m1, __uint_as_float(v.x & 0xffff0000u));
                m2 = fmaxf(m2, __uint_as_float(v.y << 16));
                m3 = fmaxf(m3, __uint_as_float(v.y & 0xffff0000u));
                m4 = fmaxf(m4, __uint_as_float(v.z << 16));
                m5 = fmaxf(m5, __uint_as_float(v.z & 0xffff0000u));
                m6 = fmaxf(m6, __uint_as_float(v.w << 16));
                m7 = fmaxf(m7, __uint_as_float(v.w & 0xffff0000u));
            }
        }

        float* op = out + (size_t)row * 512 + slice * 32 + c8;
        const f32x4 d0 = __builtin_nontemporal_load((const f32x4*)op);
        const f32x4 d1 = __builtin_nontemporal_load((const f32x4*)op + 1);
        f32x4 o0, o1;
        o0[0] = m0 + d0[0]; o0[1] = m1 + d0[1]; o0[2] = m2 + d0[2]; o0[3] = m3 + d0[3];
        o1[0] = m4 + d1[0]; o1[1] = m5 + d1[1]; o1[2] = m6 + d1[2]; o1[3] = m7 + d1[3];
        __builtin_nontemporal_store(o0, (f32x4*)op);
        __builtin_nontemporal_store(o1, (f32x4*)op + 1);
    }
}

extern "C" void kernel_launch(void* const* d_in, const int* in_sizes, int n_in,
                              void* d_out, int out_size, void* d_ws, size_t ws_size,
                              hipStream_t stream) {
    const int*   kptr = (const int*)d_in[0];
    const int*   src  = (const int*)d_in[1];
    const float* feat = (const float*)d_in[2];
    const float* Wth  = (const float*)d_in[3];
    const float* Wph  = (const float*)d_in[4];
    float* out = (float*)d_out;

    const int N = in_sizes[2] / 512;            // 65536
    const size_t slabStride = (size_t)N * 32;   // elems per 32-col slab

    // ws layout: featb 64MB | wtc 1MB | theta slabs 64MB  (129 MB total)
    unsigned short* featb = (unsigned short*)d_ws;
    unsigned short* wtc   = (unsigned short*)((char*)d_ws + (size_t)64 * 1024 * 1024);
    unsigned short* table = (unsigned short*)((char*)d_ws + (size_t)65 * 1024 * 1024);

    const int chunksPerSlice = N / 512;

    k_convert_feat<<<(N * 512) / 1024, 256, 0, stream>>>(feat, featb);
    k_prep_w<<<512, 256, 0, stream>>>(Wth, Wph, wtc);
    k_gemm<<<(N / 128) * 8, 256, 0, stream>>>(featb, wtc, table, out, slabStride);
    k_gather<<<16 * chunksPerSlice, 256, 0, stream>>>(table, out, src, kptr,
                                                      chunksPerSlice, slabStride);
}